// Round 5
// baseline (305.058 us; speedup 1.0000x reference)
//
#include <hip/hip_runtime.h>

// Problem dims (fixed by reference)
#define NB     256    // batch
#define IN1    1024
#define H1     2048
#define OUT3   1024
#define TSTEPS 50
#define KSPLIT 4

// gemm8 geometry: C[M][2048] = A@(Bhi+Blo)^T, tile 256x128, BK=64
#define KK  2048
#define GN  16        // N tiles = 2048/128
#define NTK 32        // K tiles = 2048/64

typedef __attribute__((ext_vector_type(8))) short short8;
typedef __attribute__((ext_vector_type(4))) float f32x4;

__device__ __forceinline__ unsigned short f2bf(float f) {
  unsigned u = __float_as_uint(f);
  u += 0x7FFFu + ((u >> 16) & 1u);   // round-to-nearest-even
  return (unsigned short)(u >> 16);
}
__device__ __forceinline__ float bf2f(unsigned short h) {
  return __uint_as_float(((unsigned)h) << 16);
}

__device__ __forceinline__ void gl2lds16(const void* g, void* l) {
  __builtin_amdgcn_global_load_lds(
      (const __attribute__((address_space(1))) unsigned char*)g,
      (__attribute__((address_space(3))) unsigned char*)l, 16, 0, 0);
}

// ---------------- fp32 -> bf16 hi/lo split (W2 only) ----------------
__global__ __launch_bounds__(256)
void split_kernel(const float* __restrict__ W, unsigned short* __restrict__ hi,
                  unsigned short* __restrict__ lo, int n) {
  int i = blockIdx.x * 256 + threadIdx.x;
  if (i < n) {
    float w = W[i];
    unsigned short h = f2bf(w);
    hi[i] = h;
    lo[i] = f2bf(w - bf2f(h));
  }
}

// ---------------- fp32 split-K SGEMM (layers 1 & 3) ----------------
__global__ __launch_bounds__(256)
void sgemm_splitk(const float* __restrict__ A, const float* __restrict__ B,
                  float* __restrict__ P, int M, int N, int K) {
  __shared__ float As[16][68];
  __shared__ float Bs[16][68];
  const int t  = threadIdx.x;
  const int tx = t & 15, ty = t >> 4;
  const int m0 = blockIdx.y * 64, n0 = blockIdx.x * 64;
  const int Kc = K / KSPLIT;
  const int kbeg = blockIdx.z * Kc, kend = kbeg + Kc;
  const int lr = t >> 4, lk = t & 15;
  float acc[4][4] = {};
  for (int k0 = kbeg; k0 < kend; k0 += 16) {
    #pragma unroll
    for (int i = 0; i < 4; ++i) {
      As[lk][lr + i * 16] = A[(size_t)(m0 + lr + i * 16) * K + k0 + lk];
      Bs[lk][lr + i * 16] = B[(size_t)(n0 + lr + i * 16) * K + k0 + lk];
    }
    __syncthreads();
    #pragma unroll
    for (int kk = 0; kk < 16; ++kk) {
      float4 a4 = *(const float4*)&As[kk][ty * 4];
      float4 b4 = *(const float4*)&Bs[kk][tx * 4];
      float av[4] = {a4.x, a4.y, a4.z, a4.w};
      float bv[4] = {b4.x, b4.y, b4.z, b4.w};
      #pragma unroll
      for (int i = 0; i < 4; ++i)
        #pragma unroll
        for (int j = 0; j < 4; ++j)
          acc[i][j] += av[i] * bv[j];
    }
    __syncthreads();
  }
  float* Pp = P + (size_t)blockIdx.z * M * N;
  #pragma unroll
  for (int i = 0; i < 4; ++i)
    #pragma unroll
    for (int j = 0; j < 4; ++j)
      Pp[(size_t)(m0 + ty * 4 + i) * N + n0 + tx * 4 + j] = acc[i][j];
}

// ---------------- layer-1: reduce partials + spike precompute ----------------
__global__ __launch_bounds__(256)
void sim1_kernel(const float* __restrict__ P, const float* __restrict__ b1,
                 unsigned short* __restrict__ s1all) {
  int idx = blockIdx.x * 256 + threadIdx.x;   // NB*H1 threads
  float inp = b1[idx & (H1 - 1)];
  #pragma unroll
  for (int s = 0; s < KSPLIT; ++s) inp += P[(size_t)s * (NB * H1) + idx];
  float v = 0.f;
  #pragma unroll
  for (int t = 0; t < TSTEPS; ++t) {
    v += inp;
    bool s = (v >= 1.0f);
    s1all[(size_t)t * (NB * H1) + idx] = s ? (unsigned short)0x3F80 : (unsigned short)0;
    if (s) v = 0.f;
  }
}

// ---------------- layer-2 membrane scan -> spike counts ----------------
__global__ __launch_bounds__(256)
void sim2_kernel(const float* __restrict__ A2, const float* __restrict__ b2,
                 float* __restrict__ v2s, float* __restrict__ cnt,
                 int tch, int init) {
  int idx = blockIdx.x * 256 + threadIdx.x;   // NB*H1 threads
  float v = init ? 0.f : v2s[idx];
  float c = init ? 0.f : cnt[idx];
  float bb = b2[idx & (H1 - 1)];
  for (int t = 0; t < tch; ++t) {
    v = v + A2[(size_t)t * (NB * H1) + idx];
    v = v + bb;
    if (v >= 1.0f) { c += 1.f; v = 0.f; }
  }
  v2s[idx] = v;
  cnt[idx] = c;
}

// ---------------- layer-3 epilogue: out = (sum(P) + T*b3)/T ----------------
__global__ __launch_bounds__(256)
void out_epi_kernel(const float* __restrict__ P, const float* __restrict__ b3,
                    float* __restrict__ out) {
  int idx = blockIdx.x * 256 + threadIdx.x;   // NB*OUT3 threads
  float a = 0.f;
  #pragma unroll
  for (int s = 0; s < KSPLIT; ++s) a += P[(size_t)s * (NB * OUT3) + idx];
  out[idx] = (a + (float)TSTEPS * b3[idx & (OUT3 - 1)]) * (1.0f / TSTEPS);
}

// ---------------- 8-phase dual-limb bf16 MFMA GEMM (layer 2) ----------------
// C[M][2048] = A @ Bhi^T + A @ Blo^T, fp32 accum. Tile 256x128, BK=64, 8 waves.
// 4 phases/K-tile, 2 barriers/phase. Counted vmcnt(4) placed at END of ph3,
// BEFORE the tile's final barrier: wave proves its own tile-(T+1) loads landed,
// then the barrier publishes across waves (vmcnt is per-wave; the failed round-4
// variant waited at top-of-loop AFTER the barrier -> cross-wave race).
// T2 XOR-swizzle (linear LDS dest + pre-swizzled source + XOR'd read).
__global__ __launch_bounds__(512, 2)
void gemm8(const unsigned short* __restrict__ A,
           const unsigned short* __restrict__ Bhi,
           const unsigned short* __restrict__ Blo,
           float* __restrict__ C) {
  __shared__ unsigned short lds[2][4][128 * 64];   // [buf][A0,A1,Bhi,Blo][16KB]

  // m204 bijective XCD swizzle
  const int nwg = gridDim.x * gridDim.y;
  int orig = blockIdx.y * gridDim.x + blockIdx.x;
  int q = nwg >> 3, r = nwg & 7;
  int xcd = orig & 7, rest = orig >> 3;
  int wg = (xcd < r ? xcd * (q + 1) : r * (q + 1) + (xcd - r) * q) + rest;
  const int bx = wg % GN, by = wg / GN;
  const int m0 = by * 256, n0 = bx * 128;

  const int t  = threadIdx.x;
  const int l  = t & 63, w = t >> 6;
  const int wm = w >> 2, wn = w & 3;          // 2 m-warps x 4 n-warps
  const int lr = l & 15, lq = l >> 4;
  const int lrk = lr & 7;                     // read-side XOR key
  const int sr = t >> 3, sc8 = t & 7;         // staging row / 16B-chunk
  const int scol = (sc8 ^ (sr & 7)) * 8;      // pre-swizzled source col

  auto stage = [&](const unsigned short* src, unsigned short* slot) {
    gl2lds16(src + (size_t)sr * KK + scol, slot + sr * 64 + sc8 * 8);
    gl2lds16(src + (size_t)(sr + 64) * KK + scol, slot + (sr + 64) * 64 + sc8 * 8);
  };

  const unsigned short* A0p = A + (size_t)m0 * KK;           // rows m0..+127
  const unsigned short* A1p = A + (size_t)(m0 + 128) * KK;   // rows +128..+255
  const unsigned short* Bhp = Bhi + (size_t)n0 * KK;         // rows n0..+127
  const unsigned short* Blp = Blo + (size_t)n0 * KK;

  f32x4 acc[8][2];
  #pragma unroll
  for (int m = 0; m < 8; ++m)
    #pragma unroll
    for (int c = 0; c < 2; ++c)
      acc[m][c] = (f32x4)(0.f);

  // prologue: Bhi(0),Blo(0),A0(0),A1(0),Bhi(1),Blo(1) = 12 loads (order matters).
  // vmcnt(4): oldest 8 done = ALL of tile 0; then barrier publishes cross-wave.
  stage(Bhp,      lds[0][2]);
  stage(Blp,      lds[0][3]);
  stage(A0p,      lds[0][0]);
  stage(A1p,      lds[0][1]);
  stage(Bhp + 64, lds[1][2]);
  stage(Blp + 64, lds[1][3]);
  asm volatile("s_waitcnt vmcnt(4)" ::: "memory");
  __builtin_amdgcn_s_barrier();

  #pragma unroll 1
  for (int T = 0; T < NTK; ++T) {
    const int b = T & 1;
    const unsigned short* As_ = lds[b][wm];
    const unsigned short* Bh_ = lds[b][2];
    const unsigned short* Bl_ = lds[b][3];

    short8 af[4][2], bh[2][2], bl[2][2];

    // ---- phase 0: read A r0-3 + Bhi; stage A0(T+1)->buf^1; MFMA mh0 x hi ----
    #pragma unroll
    for (int rr = 0; rr < 4; ++rr)
      #pragma unroll
      for (int s = 0; s < 2; ++s)
        af[rr][s] = *(const short8*)(As_ + (rr * 16 + lr) * 64 + ((s * 4 + lq) ^ lrk) * 8);
    #pragma unroll
    for (int c = 0; c < 2; ++c)
      #pragma unroll
      for (int s = 0; s < 2; ++s)
        bh[c][s] = *(const short8*)(Bh_ + (wn * 32 + c * 16 + lr) * 64 + ((s * 4 + lq) ^ lrk) * 8);
    if (T + 1 < NTK) stage(A0p + (T + 1) * 64, lds[b ^ 1][0]);
    __builtin_amdgcn_s_barrier();
    asm volatile("s_waitcnt lgkmcnt(0)" ::: "memory");
    __builtin_amdgcn_s_setprio(1);
    #pragma unroll
    for (int rr = 0; rr < 4; ++rr)
      #pragma unroll
      for (int c = 0; c < 2; ++c)
        #pragma unroll
        for (int s = 0; s < 2; ++s)
          acc[rr][c] = __builtin_amdgcn_mfma_f32_16x16x32_bf16(af[rr][s], bh[c][s], acc[rr][c], 0, 0, 0);
    __builtin_amdgcn_s_setprio(0);
    __builtin_amdgcn_s_barrier();

    // ---- phase 1: read Blo; stage A1(T+1)->buf^1; MFMA mh0 x lo ----
    #pragma unroll
    for (int c = 0; c < 2; ++c)
      #pragma unroll
      for (int s = 0; s < 2; ++s)
        bl[c][s] = *(const short8*)(Bl_ + (wn * 32 + c * 16 + lr) * 64 + ((s * 4 + lq) ^ lrk) * 8);
    if (T + 1 < NTK) stage(A1p + (T + 1) * 64, lds[b ^ 1][1]);
    __builtin_amdgcn_s_barrier();
    asm volatile("s_waitcnt lgkmcnt(0)" ::: "memory");
    __builtin_amdgcn_s_setprio(1);
    #pragma unroll
    for (int rr = 0; rr < 4; ++rr)
      #pragma unroll
      for (int c = 0; c < 2; ++c)
        #pragma unroll
        for (int s = 0; s < 2; ++s)
          acc[rr][c] = __builtin_amdgcn_mfma_f32_16x16x32_bf16(af[rr][s], bl[c][s], acc[rr][c], 0, 0, 0);
    __builtin_amdgcn_s_setprio(0);
    __builtin_amdgcn_s_barrier();

    // ---- phase 2: read A r4-7; stage Bhi(T+2)->buf (slot dead since ph0); MFMA mh1 x hi ----
    #pragma unroll
    for (int rr = 0; rr < 4; ++rr)
      #pragma unroll
      for (int s = 0; s < 2; ++s)
        af[rr][s] = *(const short8*)(As_ + ((rr + 4) * 16 + lr) * 64 + ((s * 4 + lq) ^ lrk) * 8);
    if (T + 2 < NTK) stage(Bhp + (T + 2) * 64, lds[b][2]);
    __builtin_amdgcn_s_barrier();
    asm volatile("s_waitcnt lgkmcnt(0)" ::: "memory");
    __builtin_amdgcn_s_setprio(1);
    #pragma unroll
    for (int rr = 0; rr < 4; ++rr)
      #pragma unroll
      for (int c = 0; c < 2; ++c)
        #pragma unroll
        for (int s = 0; s < 2; ++s)
          acc[rr + 4][c] = __builtin_amdgcn_mfma_f32_16x16x32_bf16(af[rr][s], bh[c][s], acc[rr + 4][c], 0, 0, 0);
    __builtin_amdgcn_s_setprio(0);
    __builtin_amdgcn_s_barrier();

    // ---- phase 3: stage Blo(T+2)->buf (dead since ph1); MFMA mh1 x lo;
    //      then the tile-(T+1) publish: vmcnt before the FINAL barrier ----
    if (T + 2 < NTK) stage(Blp + (T + 2) * 64, lds[b][3]);
    __builtin_amdgcn_s_barrier();
    __builtin_amdgcn_s_setprio(1);
    #pragma unroll
    for (int rr = 0; rr < 4; ++rr)
      #pragma unroll
      for (int c = 0; c < 2; ++c)
        #pragma unroll
        for (int s = 0; s < 2; ++s)
          acc[rr + 4][c] = __builtin_amdgcn_mfma_f32_16x16x32_bf16(af[rr][s], bl[c][s], acc[rr + 4][c], 0, 0, 0);
    __builtin_amdgcn_s_setprio(0);
    // FIFO: [.., Bhi(T+1), Blo(T+1), A0(T+1), A1(T+1), Bhi(T+2), Blo(T+2)]
    // vmcnt(4) -> everything except the 4 newest (tile T+2 halves) landed,
    // i.e. ALL of tile T+1. At T=NTK-2 no T+2 stages were issued -> vmcnt(0)
    // to cover A0/A1(NTK-1). At T=NTK-1 nothing left to wait for.
    if (T + 2 < NTK)      asm volatile("s_waitcnt vmcnt(4)" ::: "memory");
    else if (T + 1 < NTK) asm volatile("s_waitcnt vmcnt(0)" ::: "memory");
    __builtin_amdgcn_s_barrier();
  }

  // epilogue: C/D layout col=lane&15, row=(lane>>4)*4+j  [m89-verified]
  #pragma unroll
  for (int rr = 0; rr < 8; ++rr) {
    #pragma unroll
    for (int c = 0; c < 2; ++c) {
      int col  = n0 + wn * 32 + c * 16 + lr;
      int rowb = m0 + wm * 128 + rr * 16 + lq * 4;
      #pragma unroll
      for (int j = 0; j < 4; ++j)
        C[(size_t)(rowb + j) * KK + col] = acc[rr][c][j];
    }
  }
}

extern "C" void kernel_launch(void* const* d_in, const int* in_sizes, int n_in,
                              void* d_out, int out_size, void* d_ws, size_t ws_size,
                              hipStream_t stream) {
  const float* x  = (const float*)d_in[0];
  const float* W1 = (const float*)d_in[1];
  const float* b1 = (const float*)d_in[2];
  const float* W2 = (const float*)d_in[3];
  const float* b2 = (const float*)d_in[4];
  const float* W3 = (const float*)d_in[5];
  const float* b3 = (const float*)d_in[6];
  float* out = (float*)d_out;

  char* ws = (char*)d_ws;
  size_t off = 0;
  auto take = [&](size_t bytes) -> void* {
    void* p = ws + off;
    off += (bytes + 255) & ~(size_t)255;
    return p;
  };
  unsigned short* W2hi  = (unsigned short*)take((size_t)H1 * H1 * 2);
  unsigned short* W2lo  = (unsigned short*)take((size_t)H1 * H1 * 2);
  unsigned short* s1all = (unsigned short*)take((size_t)TSTEPS * NB * H1 * 2);
  float*          v2s   = (float*)take((size_t)NB * H1 * 4);
  float*          cnt   = (float*)take((size_t)NB * H1 * 4);
  float*          Part  = (float*)take((size_t)KSPLIT * NB * H1 * 4);  // split-K partials

  const size_t plane = (size_t)NB * H1 * 4;   // one fp32 timestep plane (2 MB)
  size_t avail = (ws_size > off) ? (ws_size - off) : 0;
  int CH = (int)(avail / plane);
  if (CH > TSTEPS) CH = TSTEPS;
  if (CH < 1) CH = 1;
  float* A2 = (float*)take((size_t)CH * plane);

  // 1) W2 bf16 hi/lo limbs
  split_kernel<<<dim3((H1 * H1 + 255) / 256), 256, 0, stream>>>(W2, W2hi, W2lo, H1 * H1);

  // 2) layer 1 in fp32: P[z] = x @ W1[:,chunk]^T (512 blocks), reduce fused in sim1
  sgemm_splitk<<<dim3(H1 / 64, NB / 64, KSPLIT), 256, 0, stream>>>(
      x, W1, Part, NB, H1, IN1);

  // 3) all layer-1 spikes for all T timesteps (elementwise-independent)
  sim1_kernel<<<dim3(NB * H1 / 256), 256, 0, stream>>>(Part, b1, s1all);

  // 4) A2[t] = s1[t] @ W2^T, both limbs in one K-pass, 8-phase schedule; then v2 scan
  for (int c0 = 0; c0 < TSTEPS; c0 += CH) {
    int ch = (TSTEPS - c0 < CH) ? (TSTEPS - c0) : CH;
    gemm8<<<dim3(GN, ch), 512, 0, stream>>>(
        s1all + (size_t)c0 * NB * H1, W2hi, W2lo, A2);
    sim2_kernel<<<dim3(NB * H1 / 256), 256, 0, stream>>>(A2, b2, v2s, cnt, ch, c0 == 0);
  }

  // 5) layer 3 in fp32: P[z] = cnt @ W3[:,chunk]^T (256 blocks) + epilogue
  sgemm_splitk<<<dim3(OUT3 / 64, NB / 64, KSPLIT), 256, 0, stream>>>(
      cnt, W3, Part, NB, OUT3, H1);
  out_epi_kernel<<<dim3(NB * OUT3 / 256), 256, 0, stream>>>(Part, b3, out);
}

// Round 6
// 289.290 us; speedup vs baseline: 1.0545x; 1.0545x over previous
//
#include <hip/hip_runtime.h>

// Problem dims (fixed by reference)
#define NB     256    // batch
#define IN1    1024
#define H1     2048
#define OUT3   1024
#define TSTEPS 50
#define KSPLIT 4      // layer-1 fp32 split-K
#define KSPL3  8      // layer-3 MFMA split-K

typedef __attribute__((ext_vector_type(8))) short short8;
typedef __attribute__((ext_vector_type(4))) float f32x4;

__device__ __forceinline__ unsigned short f2bf(float f) {
  unsigned u = __float_as_uint(f);
  u += 0x7FFFu + ((u >> 16) & 1u);   // round-to-nearest-even
  return (unsigned short)(u >> 16);
}
__device__ __forceinline__ float bf2f(unsigned short h) {
  return __uint_as_float(((unsigned)h) << 16);
}

__device__ __forceinline__ void gl2lds16(const void* g, void* l) {
  __builtin_amdgcn_global_load_lds(
      (const __attribute__((address_space(1))) unsigned char*)g,
      (__attribute__((address_space(3))) unsigned char*)l, 16, 0, 0);
}

// ---------------- fp32 -> bf16 hi/lo split ----------------
__global__ __launch_bounds__(256)
void split_kernel(const float* __restrict__ W, unsigned short* __restrict__ hi,
                  unsigned short* __restrict__ lo, int n) {
  int i = blockIdx.x * 256 + threadIdx.x;
  if (i < n) {
    float w = W[i];
    unsigned short h = f2bf(w);
    hi[i] = h;
    lo[i] = f2bf(w - bf2f(h));
  }
}

// ---------------- fp32 -> bf16 (exact for small ints) ----------------
__global__ __launch_bounds__(256)
void cvt_bf_kernel(const float* __restrict__ in, unsigned short* __restrict__ out, int n) {
  int i = blockIdx.x * 256 + threadIdx.x;
  if (i < n) out[i] = f2bf(in[i]);
}

// ---------------- fp32 split-K SGEMM (layer 1) ----------------
__global__ __launch_bounds__(256)
void sgemm_splitk(const float* __restrict__ A, const float* __restrict__ B,
                  float* __restrict__ P, int M, int N, int K) {
  __shared__ float As[16][68];
  __shared__ float Bs[16][68];
  const int t  = threadIdx.x;
  const int tx = t & 15, ty = t >> 4;
  const int m0 = blockIdx.y * 64, n0 = blockIdx.x * 64;
  const int Kc = K / KSPLIT;
  const int kbeg = blockIdx.z * Kc, kend = kbeg + Kc;
  const int lr = t >> 4, lk = t & 15;
  float acc[4][4] = {};
  for (int k0 = kbeg; k0 < kend; k0 += 16) {
    #pragma unroll
    for (int i = 0; i < 4; ++i) {
      As[lk][lr + i * 16] = A[(size_t)(m0 + lr + i * 16) * K + k0 + lk];
      Bs[lk][lr + i * 16] = B[(size_t)(n0 + lr + i * 16) * K + k0 + lk];
    }
    __syncthreads();
    #pragma unroll
    for (int kk = 0; kk < 16; ++kk) {
      float4 a4 = *(const float4*)&As[kk][ty * 4];
      float4 b4 = *(const float4*)&Bs[kk][tx * 4];
      float av[4] = {a4.x, a4.y, a4.z, a4.w};
      float bv[4] = {b4.x, b4.y, b4.z, b4.w};
      #pragma unroll
      for (int i = 0; i < 4; ++i)
        #pragma unroll
        for (int j = 0; j < 4; ++j)
          acc[i][j] += av[i] * bv[j];
    }
    __syncthreads();
  }
  float* Pp = P + (size_t)blockIdx.z * M * N;
  #pragma unroll
  for (int i = 0; i < 4; ++i)
    #pragma unroll
    for (int j = 0; j < 4; ++j)
      Pp[(size_t)(m0 + ty * 4 + i) * N + n0 + tx * 4 + j] = acc[i][j];
}

// ---------------- layer-1: reduce partials + spike precompute ----------------
__global__ __launch_bounds__(256)
void sim1_kernel(const float* __restrict__ P, const float* __restrict__ b1,
                 unsigned short* __restrict__ s1all) {
  int idx = blockIdx.x * 256 + threadIdx.x;   // NB*H1 threads
  float inp = b1[idx & (H1 - 1)];
  #pragma unroll
  for (int s = 0; s < KSPLIT; ++s) inp += P[(size_t)s * (NB * H1) + idx];
  float v = 0.f;
  #pragma unroll
  for (int t = 0; t < TSTEPS; ++t) {
    v += inp;
    bool s = (v >= 1.0f);
    s1all[(size_t)t * (NB * H1) + idx] = s ? (unsigned short)0x3F80 : (unsigned short)0;
    if (s) v = 0.f;
  }
}

// ---------------- layer-2 membrane scan -> spike counts ----------------
__global__ __launch_bounds__(256)
void sim2_kernel(const float* __restrict__ A2, const float* __restrict__ b2,
                 float* __restrict__ v2s, float* __restrict__ cnt,
                 int tch, int init) {
  int idx = blockIdx.x * 256 + threadIdx.x;   // NB*H1 threads
  float v = init ? 0.f : v2s[idx];
  float c = init ? 0.f : cnt[idx];
  float bb = b2[idx & (H1 - 1)];
  for (int t = 0; t < tch; ++t) {
    v = v + A2[(size_t)t * (NB * H1) + idx];
    v = v + bb;
    if (v >= 1.0f) { c += 1.f; v = 0.f; }
  }
  v2s[idx] = v;
  cnt[idx] = c;
}

// ---------------- layer-3 epilogue: out = (sum_z P[z] + T*b3)/T ----------------
__global__ __launch_bounds__(256)
void out_epi_kernel(const float* __restrict__ P, const float* __restrict__ b3,
                    float* __restrict__ out) {
  int idx = blockIdx.x * 256 + threadIdx.x;   // NB*OUT3 threads
  float a = 0.f;
  #pragma unroll
  for (int s = 0; s < KSPL3; ++s) a += P[(size_t)s * (NB * OUT3) + idx];
  out[idx] = (a + (float)TSTEPS * b3[idx & (OUT3 - 1)]) * (1.0f / TSTEPS);
}

// ---------------- bf16 dual-limb MFMA GEMM (layers 2 & 3) ----------------
// C[z][M][N] = A @ B0[:,chunk_z]^T + A @ B1[:,chunk_z]^T, fp32 accum.
// Kc = K-chunk per z (Kc==K, grid.z==1 -> plain full-K GEMM, round-3 proven).
// 128x128 tile, BK=64, 4 waves (2x2), 16x16x32 MFMA, global_load_lds w=16.
// T2 XOR-swizzle (linear LDS dest + pre-swizzled source + XOR'd read).
// XCD-bijective blockIdx swizzle (T1) when grid.z==1 and nwg%8==0.
__global__ __launch_bounds__(256)
void gemm_mfma(const unsigned short* __restrict__ A0,
               const unsigned short* __restrict__ B0,
               const unsigned short* __restrict__ B1,
               float* __restrict__ C, int M, int N, int K, int Kc) {
  __shared__ unsigned short As[128 * 64];
  __shared__ unsigned short Bs[2 * 128 * 64];

  // T1: XCD-aware contiguous-chunk swizzle (bijective when nwg%8==0)
  const int gx  = gridDim.x;
  const int nwg = gx * gridDim.y;
  int wg = blockIdx.y * gx + blockIdx.x;
  if (gridDim.z == 1 && (nwg & 7) == 0) wg = (wg & 7) * (nwg >> 3) + (wg >> 3);
  const int bx = wg % gx, by = wg / gx;
  const int m0 = by * 128, n0 = bx * 128;
  const int kbeg = blockIdx.z * Kc, kend = kbeg + Kc;

  const int t  = threadIdx.x;
  const int l  = t & 63;
  const int w  = t >> 6;
  const int wr = w >> 1, wc = w & 1;
  const int lr = l & 15;             // fragment row/col within 16
  const int kx = lr & 7;             // T2 read-side XOR (per-lane constant)
  // staging decomposition: thread t handles row r8(+32i), 16B-chunk c8
  const int r8   = t >> 3, c8 = t & 7;
  const int scol = (c8 ^ (r8 & 7)) * 8;   // pre-swizzled source column (bf16 elems)

  f32x4 acc[4][4];
  #pragma unroll
  for (int m = 0; m < 4; ++m)
    #pragma unroll
    for (int n = 0; n < 4; ++n)
      acc[m][n] = (f32x4)(0.f);

  #pragma unroll 1
  for (int k0 = kbeg; k0 < kend; k0 += 64) {
    // ---- stage tiles (linear LDS dest; swizzled global source) ----
    #pragma unroll
    for (int i = 0; i < 4; ++i) {
      int row = i * 32 + r8;
      gl2lds16(A0 + (size_t)(m0 + row) * K + k0 + scol, As + row * 64 + c8 * 8);
    }
    #pragma unroll
    for (int i = 0; i < 4; ++i) {
      int row = i * 32 + r8;
      gl2lds16(B0 + (size_t)(n0 + row) * K + k0 + scol, Bs + row * 64 + c8 * 8);
    }
    #pragma unroll
    for (int i = 0; i < 4; ++i) {
      int row = i * 32 + r8;
      gl2lds16(B1 + (size_t)(n0 + row) * K + k0 + scol, Bs + 128 * 64 + row * 64 + c8 * 8);
    }
    __syncthreads();

    // ---- compute: 2 k-substeps x 16 frag-pairs x 2 limb products ----
    #pragma unroll
    for (int ks = 0; ks < 2; ++ks) {
      const int kc = ks * 4 + (l >> 4);          // logical 16B k-chunk 0..7
      const int ko = (kc ^ kx) * 8;              // swizzled k offset (bf16 elems)
      short8 a0f[4], b0f[4], b1f[4];
      #pragma unroll
      for (int m = 0; m < 4; ++m)
        a0f[m] = *(const short8*)(As + (wr * 64 + m * 16 + lr) * 64 + ko);
      #pragma unroll
      for (int n = 0; n < 4; ++n)
        b0f[n] = *(const short8*)(Bs + (wc * 64 + n * 16 + lr) * 64 + ko);
      #pragma unroll
      for (int m = 0; m < 4; ++m)
        #pragma unroll
        for (int n = 0; n < 4; ++n)
          acc[m][n] = __builtin_amdgcn_mfma_f32_16x16x32_bf16(a0f[m], b0f[n], acc[m][n], 0, 0, 0);
      #pragma unroll
      for (int n = 0; n < 4; ++n)
        b1f[n] = *(const short8*)(Bs + 128 * 64 + (wc * 64 + n * 16 + lr) * 64 + ko);
      #pragma unroll
      for (int m = 0; m < 4; ++m)
        #pragma unroll
        for (int n = 0; n < 4; ++n)
          acc[m][n] = __builtin_amdgcn_mfma_f32_16x16x32_bf16(a0f[m], b1f[n], acc[m][n], 0, 0, 0);
    }
    __syncthreads();
  }

  // epilogue: C/D layout col=lane&15, row=(lane>>4)*4+j  [m89-verified]
  float* Cp = C + (size_t)blockIdx.z * M * N;
  const int crow = (l >> 4) * 4;
  #pragma unroll
  for (int m = 0; m < 4; ++m) {
    #pragma unroll
    for (int n = 0; n < 4; ++n) {
      int col  = n0 + wc * 64 + n * 16 + lr;
      int rowb = m0 + wr * 64 + m * 16 + crow;
      #pragma unroll
      for (int j = 0; j < 4; ++j)
        Cp[(size_t)(rowb + j) * N + col] = acc[m][n][j];
    }
  }
}

extern "C" void kernel_launch(void* const* d_in, const int* in_sizes, int n_in,
                              void* d_out, int out_size, void* d_ws, size_t ws_size,
                              hipStream_t stream) {
  const float* x  = (const float*)d_in[0];
  const float* W1 = (const float*)d_in[1];
  const float* b1 = (const float*)d_in[2];
  const float* W2 = (const float*)d_in[3];
  const float* b2 = (const float*)d_in[4];
  const float* W3 = (const float*)d_in[5];
  const float* b3 = (const float*)d_in[6];
  float* out = (float*)d_out;

  char* ws = (char*)d_ws;
  size_t off = 0;
  auto take = [&](size_t bytes) -> void* {
    void* p = ws + off;
    off += (bytes + 255) & ~(size_t)255;
    return p;
  };
  unsigned short* W2hi  = (unsigned short*)take((size_t)H1 * H1 * 2);
  unsigned short* W2lo  = (unsigned short*)take((size_t)H1 * H1 * 2);
  unsigned short* W3hi  = (unsigned short*)take((size_t)OUT3 * H1 * 2);
  unsigned short* W3lo  = (unsigned short*)take((size_t)OUT3 * H1 * 2);
  unsigned short* s1all = (unsigned short*)take((size_t)TSTEPS * NB * H1 * 2);
  float*          v2s   = (float*)take((size_t)NB * H1 * 4);
  float*          cnt   = (float*)take((size_t)NB * H1 * 4);
  unsigned short* cntbf = (unsigned short*)take((size_t)NB * H1 * 2);
  // Part shared: layer-1 (KSPLIT x NB x H1) and layer-3 (KSPL3 x NB x OUT3), both 8 MB
  size_t part_bytes = (size_t)KSPLIT * NB * H1 * 4;
  size_t part3_bytes = (size_t)KSPL3 * NB * OUT3 * 4;
  float* Part = (float*)take(part_bytes > part3_bytes ? part_bytes : part3_bytes);

  const size_t plane = (size_t)NB * H1 * 4;   // one fp32 timestep plane (2 MB)
  size_t avail = (ws_size > off) ? (ws_size - off) : 0;
  int CH = (int)(avail / plane);
  if (CH > TSTEPS) CH = TSTEPS;
  if (CH < 1) CH = 1;
  float* A2 = (float*)take((size_t)CH * plane);

  // 1) W2, W3 bf16 hi/lo limbs
  split_kernel<<<dim3((H1 * H1 + 255) / 256), 256, 0, stream>>>(W2, W2hi, W2lo, H1 * H1);
  split_kernel<<<dim3((OUT3 * H1 + 255) / 256), 256, 0, stream>>>(W3, W3hi, W3lo, OUT3 * H1);

  // 2) layer 1 in fp32: P[z] = x @ W1[:,chunk]^T (512 blocks), reduce fused in sim1
  sgemm_splitk<<<dim3(H1 / 64, NB / 64, KSPLIT), 256, 0, stream>>>(
      x, W1, Part, NB, H1, IN1);

  // 3) all layer-1 spikes for all T timesteps (elementwise-independent)
  sim1_kernel<<<dim3(NB * H1 / 256), 256, 0, stream>>>(Part, b1, s1all);

  // 4) A2[t] = s1[t] @ W2^T, both limbs in one K-pass; then v2 scan
  for (int c0 = 0; c0 < TSTEPS; c0 += CH) {
    int ch = (TSTEPS - c0 < CH) ? (TSTEPS - c0) : CH;
    gemm_mfma<<<dim3(H1 / 128, ch * NB / 128), 256, 0, stream>>>(
        s1all + (size_t)c0 * NB * H1, W2hi, W2lo, A2, ch * NB, H1, H1, H1);
    sim2_kernel<<<dim3(NB * H1 / 256), 256, 0, stream>>>(A2, b2, v2s, cnt, ch, c0 == 0);
  }

  // 5) layer 3: cnt (exact in bf16) @ (W3hi+W3lo)^T via split-K MFMA + reduce
  cvt_bf_kernel<<<dim3(NB * H1 / 256), 256, 0, stream>>>(cnt, cntbf, NB * H1);
  gemm_mfma<<<dim3(OUT3 / 128, NB / 128, KSPL3), 256, 0, stream>>>(
      cntbf, W3hi, W3lo, Part, NB, OUT3, H1, H1 / KSPL3);
  out_epi_kernel<<<dim3(NB * OUT3 / 256), 256, 0, stream>>>(Part, b3, out);
}